// Round 8
// baseline (73.665 us; speedup 1.0000x reference)
//
#include <hip/hip_runtime.h>
#include <hip/hip_bf16.h>
#include <math.h>

#define M 4096
#define ALPHA 0.2f
#define L2E 1.4426950408889634f

typedef __attribute__((ext_vector_type(8))) short bf16x8_t;   // 8 bf16 = 4 VGPRs
typedef __attribute__((ext_vector_type(4))) float f32x4_t;    // MFMA accumulator

#define EXP2F(x) __builtin_amdgcn_exp2f(x)   // v_exp_f32: 2^x

// round-to-nearest-even float -> bf16 bits (cold paths)
__device__ inline unsigned short f2bf(float f) {
    unsigned int u = __float_as_uint(f);
    u = (u + 0x7fffu + ((u >> 16) & 1u)) >> 16;
    return (unsigned short)u;
}
// round-half-up float -> bf16 bits (hot path; p >= 0 finite)
__device__ inline unsigned short f2bf_fast(float f) {
    return (unsigned short)((__float_as_uint(f) + 0x8000u) >> 16);
}

// ---------------- fused: Wh1 = h0@W1 (regs), WhB1 frag scatter, s_i/s_k ----------------
template <int DIN, int F>
__global__ __launch_bounds__(256) void fused_in_kernel(const float* __restrict__ h0,
                                                       const float* __restrict__ W,
                                                       const float* __restrict__ a,
                                                       unsigned short* __restrict__ WhB,
                                                       float* __restrict__ s_i,
                                                       float* __restrict__ s_k) {
    int wave = threadIdx.x >> 6, lane = threadIdx.x & 63;
    int i = blockIdx.x * 4 + wave;
    float acc = 0.f;                                   // Wh[i][lane]
#pragma unroll
    for (int j = 0; j < DIN; j++)
        acc += h0[(size_t)i * DIN + j] * W[j * F + lane];
    float vi = acc * a[lane], vk = acc * a[F + lane];
#pragma unroll
    for (int off = 32; off; off >>= 1) { vi += __shfl_xor(vi, off); vk += __shfl_xor(vk, off); }
    if (lane == 0) { s_i[i] = vi; s_k[i] = vk; }
    // scatter into B-fragment layout: [k5][fblk][lane(=kg*16+fl)][j]
    constexpr int NFB = F / 16;
    int fb = lane >> 4, fl = lane & 15;
    size_t idx = (((size_t)(i >> 5) * NFB + fb) * 64 + (((i & 31) >> 3) * 16 + fl)) * 8 + (i & 7);
    WhB[idx] = f2bf(acc);
}

// ---------------- MFMA attention @ Wh, unnormalized P + row-sum side output ----------------
// READ_ADJ=true (layer 1): reads its disjoint adj tile directly, bit-packs into LDS,
// writes packedT for layer 2. READ_ADJ=false (layer 2): stages packedT tile into LDS.
// P_unnorm = exp2(leaky(si+sk)*L2E - rl2), rl2 = leaky(si+skmax)*L2E (block-computed,
// bitwise identical across blocks). Normalization (1/S) applied in the reduce kernels.
template <int F, int KSPLIT, bool READ_ADJ>
__global__ __launch_bounds__(256) void attn_mfma_kernel(const unsigned short* __restrict__ WhB,
                                                        const float* __restrict__ s_i,
                                                        const float* __restrict__ s_k,
                                                        const int* __restrict__ adj,
                                                        unsigned int* __restrict__ packedT,
                                                        float* __restrict__ partial,
                                                        float* __restrict__ partialS) {
    constexpr int NFB = F / 16;
    constexpr int KLEN = M / KSPLIT;
    constexpr int NW = KLEN / 32;                      // mask words per row (16)
    constexpr int NRB = M / 64;
    __shared__ unsigned int mask_lds[64][NW + 1];      // pad -> conflict-free
    __shared__ float wred[4];
    int tid = threadIdx.x, wave = tid >> 6, lane = tid & 63;
    int rb = blockIdx.x % NRB, ks = blockIdx.x / NRB;
    int R0b = rb * 64;
    int k_begin = ks * KLEN;

    // in-block global skmax (deterministic, identical in every block)
    float m = -INFINITY;
    for (int j = tid; j < M; j += 256) m = fmaxf(m, s_k[j]);
#pragma unroll
    for (int off = 32; off; off >>= 1) m = fmaxf(m, __shfl_xor(m, off));
    if (lane == 0) wred[wave] = m;

    // ---- stage mask tile into LDS ----
    if (READ_ADJ) {
#pragma unroll 4
        for (int r16 = 0; r16 < 16; r16++) {
            int rloc = wave * 16 + r16;
            const int4* arow = (const int4*)(adj + (size_t)(R0b + rloc) * M + k_begin);
#pragma unroll
            for (int c = 0; c < 2; c++) {
                int4 av = arow[c * 64 + lane];
                unsigned int nib = (av.x > 0 ? 1u : 0u) | (av.y > 0 ? 2u : 0u) |
                                   (av.z > 0 ? 4u : 0u) | (av.w > 0 ? 8u : 0u);
                unsigned int sh = nib << ((lane & 7) * 4);
                sh |= __shfl_xor(sh, 1);
                sh |= __shfl_xor(sh, 2);
                sh |= __shfl_xor(sh, 4);
                if ((lane & 7) == 0) mask_lds[rloc][c * 8 + (lane >> 3)] = sh;
            }
        }
    } else {
#pragma unroll
        for (int q = 0; q < 4; q++) {
            int lin = q * 256 + tid;
            int st = lin >> 6, r = lin & 63;
            mask_lds[r][st] = packedT[(size_t)(ks * NW + st) * M + R0b + r];
        }
    }
    __syncthreads();
    if (READ_ADJ) {                                    // coalesced packedT writeback
#pragma unroll
        for (int q = 0; q < 4; q++) {
            int lin = q * 256 + tid;
            int st = lin >> 6, r = lin & 63;
            packedT[(size_t)(ks * NW + st) * M + R0b + r] = mask_lds[r][st];
        }
    }
    float skmax = fmaxf(fmaxf(wred[0], wred[1]), fmaxf(wred[2], wred[3]));

    int R0 = R0b + wave * 16;
    int fl = lane & 15;
    int row = R0 + fl;                                 // A-operand row for this lane
    int kg = lane >> 4;                                // k-group 0..3
    float si = s_i[row];
    float xm = si + skmax;
    float rl2 = fmaxf(xm, ALPHA * xm) * L2E;           // log2-domain row-max bound
    f32x4_t acc[NFB];
#pragma unroll
    for (int fb = 0; fb < NFB; fb++) acc[fb] = (f32x4_t)0.f;
    float rsum = 0.f;
    for (int st = 0; st < NW; st++) {
        int kb = k_begin + st * 32;
        float4 sa = *(const float4*)&s_k[kb + kg * 8];
        float4 sb = *(const float4*)&s_k[kb + kg * 8 + 4];
        unsigned int word = mask_lds[wave * 16 + fl][st];
        float sv[8] = { sa.x, sa.y, sa.z, sa.w, sb.x, sb.y, sb.z, sb.w };
        union { bf16x8_t v; unsigned short u[8]; } af;
#pragma unroll
        for (int j = 0; j < 8; j++) {
            float x = si + sv[j];
            float e = fmaxf(x, ALPHA * x);             // leakyrelu
            float p = EXP2F(fmaf(e, L2E, -rl2));       // unnormalized weight <= 1
            p = ((word >> (kg * 8 + j)) & 1u) ? p : 0.f;
            rsum += p;
            af.u[j] = f2bf_fast(p);
        }
        const unsigned short* bp = WhB + (size_t)(kb >> 5) * (NFB * 512) + (size_t)lane * 8;
#pragma unroll
        for (int fb = 0; fb < NFB; fb++) {
            bf16x8_t bfrag = *(const bf16x8_t*)(bp + (size_t)fb * 512);
            acc[fb] = __builtin_amdgcn_mfma_f32_16x16x32_bf16(af.v, bfrag, acc[fb], 0, 0, 0);
        }
    }
    // row-sum: lanes {l, l+16, l+32, l+48} hold partials of row R0+l
    rsum += __shfl_xor(rsum, 16);
    rsum += __shfl_xor(rsum, 32);
    if (lane < 16) partialS[(size_t)ks * M + R0 + lane] = rsum;
    // D layout: col = lane&15, row = (lane>>4)*4 + r
#pragma unroll
    for (int fb = 0; fb < NFB; fb++)
#pragma unroll
        for (int r = 0; r < 4; r++) {
            int ro = R0 + kg * 4 + r;
            partial[((size_t)ks * M + ro) * F + fb * 16 + fl] = acc[fb][r];
        }
}

// ---------------- fused: reduce partial1 -> normalize -> h1 (ELU) -> Wh2, WhB2, si2, sk2 ----
template <int KSPLIT>
__global__ __launch_bounds__(256) void fused_mid_kernel(const float* __restrict__ partial,
                                                        const float* __restrict__ partialS,
                                                        const float* __restrict__ W2,
                                                        const float* __restrict__ a2,
                                                        unsigned short* __restrict__ WhB2,
                                                        float* __restrict__ s_i2,
                                                        float* __restrict__ s_k2) {
    __shared__ float h_lds[4][64];
    int wave = threadIdx.x >> 6, lane = threadIdx.x & 63;
    int i = blockIdx.x * 4 + wave;
    float S = 0.f;
#pragma unroll
    for (int ks = 0; ks < KSPLIT; ks++) S += partialS[(size_t)ks * M + i];
    float rinv = S > 0.f ? 1.f / S : 0.f;
    float hv = 0.f;
#pragma unroll
    for (int ks = 0; ks < KSPLIT; ks++) hv += partial[((size_t)ks * M + i) * 64 + lane];
    hv *= rinv;
    hv = hv > 0.f ? hv : (__expf(hv) - 1.f);           // ELU -> h1[i][lane]
    h_lds[wave][lane] = hv;
    __syncthreads();
    int g = lane & 31, half = lane >> 5;
    float w2acc = 0.f;                                 // Wh2[i][g], split f-range by half
#pragma unroll
    for (int f = 0; f < 32; f++) {
        float hf = h_lds[wave][half * 32 + f];
        w2acc += hf * W2[(half * 32 + f) * 32 + g];
    }
    w2acc += __shfl_xor(w2acc, 32);
    float vi = w2acc * a2[g], vk = w2acc * a2[32 + g];
#pragma unroll
    for (int off = 16; off; off >>= 1) { vi += __shfl_xor(vi, off); vk += __shfl_xor(vk, off); }
    if (lane == 0) { s_i2[i] = vi; s_k2[i] = vk; }
    if (half == 0) {
        size_t idx = (((size_t)(i >> 5) * 2 + (g >> 4)) * 64 + (((i & 31) >> 3) * 16 + (g & 15))) * 8 + (i & 7);
        WhB2[idx] = f2bf(w2acc);
    }
}

// ---------------- fused: reduce partial2 -> normalize -> hL (ELU) -> out tail + omega dots ----
template <int KSPLIT>
__global__ __launch_bounds__(256) void fused_out_kernel(const float* __restrict__ partial,
                                                        const float* __restrict__ partialS,
                                                        const float* __restrict__ omega,
                                                        float* __restrict__ hL_out,
                                                        float* __restrict__ p_i,
                                                        float* __restrict__ p_k) {
    int wave = threadIdx.x >> 6, lane = threadIdx.x & 63;
    int i = blockIdx.x * 4 + wave;
    int g = lane & 31, half = lane >> 5;
    float S = 0.f;
#pragma unroll
    for (int ks = 0; ks < KSPLIT; ks++) S += partialS[(size_t)ks * M + i];
    float rinv = S > 0.f ? 1.f / S : 0.f;
    float hv = 0.f;
#pragma unroll
    for (int h = 0; h < KSPLIT / 2; h++) {
        int ks = half * (KSPLIT / 2) + h;
        hv += partial[((size_t)ks * M + i) * 32 + g];
    }
    hv += __shfl_xor(hv, 32);
    hv *= rinv;
    hv = hv > 0.f ? hv : (__expf(hv) - 1.f);
    if (half == 0) hL_out[(size_t)i * 32 + g] = hv;
    float vi = hv * omega[g], vk = hv * omega[32 + g];
#pragma unroll
    for (int off = 16; off; off >>= 1) { vi += __shfl_xor(vi, off); vk += __shfl_xor(vk, off); }
    if (lane == 0) { p_i[i] = vi; p_k[i] = vk; }
}

// ---------------- final pairwise sigmoid (grid-stride x4) ----------------
__global__ __launch_bounds__(256) void pred_kernel(const float* __restrict__ p_i,
                                                   const float* __restrict__ p_k,
                                                   float* __restrict__ out) {
    int gid = blockIdx.x * 256 + threadIdx.x;          // 0 .. M*M/16-1
#pragma unroll
    for (int t = 0; t < 4; t++) {
        int idx4 = gid + t * (M * M / 16);
        int i = idx4 / (M / 4);
        int k4 = (idx4 % (M / 4)) * 4;
        float pi = p_i[i];
        float4 pk = *(const float4*)&p_k[k4];
        float4 o;
        o.x = 1.f / (1.f + __expf(-(pi + pk.x)));
        o.y = 1.f / (1.f + __expf(-(pi + pk.y)));
        o.z = 1.f / (1.f + __expf(-(pi + pk.z)));
        o.w = 1.f / (1.f + __expf(-(pi + pk.w)));
        *(float4*)&out[(size_t)i * M + k4] = o;
    }
}

extern "C" void kernel_launch(void* const* d_in, const int* in_sizes, int n_in,
                              void* d_out, int out_size, void* d_ws, size_t ws_size,
                              hipStream_t stream) {
    const float* h0    = (const float*)d_in[0];
    const int*   adj   = (const int*)d_in[1];
    const float* W1    = (const float*)d_in[2];
    const float* a1    = (const float*)d_in[3];
    const float* W2    = (const float*)d_in[4];
    const float* a2    = (const float*)d_in[5];
    const float* omega = (const float*)d_in[6];
    float* out = (float*)d_out;

    char* ws = (char*)d_ws;
    unsigned int*   packedT = (unsigned int*)(ws + 0);         // 2 MB (transposed bits)
    unsigned short* WhB1    = (unsigned short*)(ws + 2097152); // 512 KB
    unsigned short* WhB2    = (unsigned short*)(ws + 2621440); // 256 KB
    float* si1 = (float*)(ws + 2883584);
    float* sk1 = (float*)(ws + 2899968);
    float* si2 = (float*)(ws + 2916352);
    float* sk2 = (float*)(ws + 2932736);
    float* pi  = (float*)(ws + 2949120);
    float* pk  = (float*)(ws + 2965504);
    float* pS1 = (float*)(ws + 2981888);   // KS*M*4 = 128 KB
    float* pS2 = (float*)(ws + 3112960);   // 128 KB

    float* partial = out;          // d_out as split-K scratch (pred overwrites later)
    constexpr int KS = 8;

    // layer 1 (F=64): attn reads adj directly (its tiles partition the matrix),
    // packs bits to LDS, and emits packedT for layer 2.
    fused_in_kernel<64, 64><<<M / 4, 256, 0, stream>>>(h0, W1, a1, WhB1, si1, sk1);
    attn_mfma_kernel<64, KS, true><<<(M / 64) * KS, 256, 0, stream>>>(WhB1, si1, sk1, adj,
                                                                      packedT, partial, pS1);

    // layer 2 (F=32), fused with layer-1 normalize+reduce
    fused_mid_kernel<KS><<<M / 4, 256, 0, stream>>>(partial, pS1, W2, a2, WhB2, si2, sk2);
    attn_mfma_kernel<32, KS, false><<<(M / 64) * KS, 256, 0, stream>>>(WhB2, si2, sk2, nullptr,
                                                                       packedT, partial, pS2);

    // link prediction
    fused_out_kernel<KS><<<M / 4, 256, 0, stream>>>(partial, pS2, omega, out + (size_t)M * M, pi, pk);
    pred_kernel<<<M * M / 16 / 256, 256, 0, stream>>>(pi, pk, out);
}

// Round 9
// 69.755 us; speedup vs baseline: 1.0560x; 1.0560x over previous
//
#include <hip/hip_runtime.h>
#include <hip/hip_bf16.h>
#include <math.h>

#define M 4096
#define ALPHA 0.2f
#define L2E 1.4426950408889634f

typedef __attribute__((ext_vector_type(8))) short bf16x8_t;   // 8 bf16 = 4 VGPRs
typedef __attribute__((ext_vector_type(4))) float f32x4_t;    // MFMA accumulator

#define EXP2F(x) __builtin_amdgcn_exp2f(x)   // v_exp_f32: 2^x

// round-to-nearest-even float -> bf16 bits (cold paths)
__device__ inline unsigned short f2bf(float f) {
    unsigned int u = __float_as_uint(f);
    u = (u + 0x7fffu + ((u >> 16) & 1u)) >> 16;
    return (unsigned short)u;
}
// round-half-up float -> bf16 bits (hot path; p >= 0 finite)
__device__ inline unsigned short f2bf_fast(float f) {
    return (unsigned short)((__float_as_uint(f) + 0x8000u) >> 16);
}

// ---------------- massively-parallel pack: adj -> packedT bitmask (2 MB) ----------------
// 16384 blocks; each thread one int4; 8-lane shfl merge -> one word per 8 lanes.
__global__ __launch_bounds__(256) void pack_kernel(const int* __restrict__ adj,
                                                   unsigned int* __restrict__ packedT) {
    int g = blockIdx.x * 256 + threadIdx.x;            // int4 index over M*M/4
    int lane = threadIdx.x & 63;
    int4 av = ((const int4*)adj)[g];
    unsigned int nib = (av.x > 0 ? 1u : 0u) | (av.y > 0 ? 2u : 0u) |
                       (av.z > 0 ? 4u : 0u) | (av.w > 0 ? 8u : 0u);
    unsigned int sh = nib << ((lane & 7) * 4);
    sh |= __shfl_xor(sh, 1);
    sh |= __shfl_xor(sh, 2);
    sh |= __shfl_xor(sh, 4);
    if ((lane & 7) == 0) {
        int kw = (g >> 3) & 127;                       // 32-bit word index along k
        int i  = g >> 10;                              // row (M/4 = 1024 int4 per row)
        packedT[(size_t)kw * M + i] = sh;
    }
}

// ---------------- fused: Wh1 = h0@W1 (regs), WhB1 frag scatter, s_i/s_k ----------------
template <int DIN, int F>
__global__ __launch_bounds__(256) void fused_in_kernel(const float* __restrict__ h0,
                                                       const float* __restrict__ W,
                                                       const float* __restrict__ a,
                                                       unsigned short* __restrict__ WhB,
                                                       float* __restrict__ s_i,
                                                       float* __restrict__ s_k) {
    int wave = threadIdx.x >> 6, lane = threadIdx.x & 63;
    int i = blockIdx.x * 4 + wave;
    float acc = 0.f;                                   // Wh[i][lane]
#pragma unroll
    for (int j = 0; j < DIN; j++)
        acc += h0[(size_t)i * DIN + j] * W[j * F + lane];
    float vi = acc * a[lane], vk = acc * a[F + lane];
#pragma unroll
    for (int off = 32; off; off >>= 1) { vi += __shfl_xor(vi, off); vk += __shfl_xor(vk, off); }
    if (lane == 0) { s_i[i] = vi; s_k[i] = vk; }
    // scatter into B-fragment layout: [k5][fblk][lane(=kg*16+fl)][j]
    constexpr int NFB = F / 16;
    int fb = lane >> 4, fl = lane & 15;
    size_t idx = (((size_t)(i >> 5) * NFB + fb) * 64 + (((i & 31) >> 3) * 16 + fl)) * 8 + (i & 7);
    WhB[idx] = f2bf(acc);
}

// ---------------- MFMA attention @ Wh, unnormalized P + row-sum side output ----------------
// Stages its packedT tile into LDS (coalesced). P_unnorm = exp2(leaky(si+sk)*L2E - rl2),
// rl2 = leaky(si+skmax)*L2E (block-computed, bitwise identical across blocks).
// Normalization (1/S) applied in the reduce kernels.
template <int F, int KSPLIT>
__global__ __launch_bounds__(256) void attn_mfma_kernel(const unsigned short* __restrict__ WhB,
                                                        const float* __restrict__ s_i,
                                                        const float* __restrict__ s_k,
                                                        const unsigned int* __restrict__ packedT,
                                                        float* __restrict__ partial,
                                                        float* __restrict__ partialS) {
    constexpr int NFB = F / 16;
    constexpr int KLEN = M / KSPLIT;
    constexpr int NW = KLEN / 32;                      // mask words per row (16)
    constexpr int NRB = M / 64;
    __shared__ unsigned int mask_lds[64][NW + 1];      // pad -> conflict-free
    __shared__ float wred[4];
    int tid = threadIdx.x, wave = tid >> 6, lane = tid & 63;
    int rb = blockIdx.x % NRB, ks = blockIdx.x / NRB;
    int R0b = rb * 64;
    int k_begin = ks * KLEN;

    // in-block global skmax (deterministic, identical in every block)
    float m = -INFINITY;
    for (int j = tid; j < M; j += 256) m = fmaxf(m, s_k[j]);
#pragma unroll
    for (int off = 32; off; off >>= 1) m = fmaxf(m, __shfl_xor(m, off));
    if (lane == 0) wred[wave] = m;

    // stage mask tile (coalesced: 64 consecutive rows per word-column)
#pragma unroll
    for (int q = 0; q < 4; q++) {
        int lin = q * 256 + tid;
        int st = lin >> 6, r = lin & 63;
        mask_lds[r][st] = packedT[(size_t)(ks * NW + st) * M + R0b + r];
    }
    __syncthreads();
    float skmax = fmaxf(fmaxf(wred[0], wred[1]), fmaxf(wred[2], wred[3]));

    int R0 = R0b + wave * 16;
    int fl = lane & 15;
    int row = R0 + fl;                                 // A-operand row for this lane
    int kg = lane >> 4;                                // k-group 0..3
    float si = s_i[row];
    float xm = si + skmax;
    float rl2 = fmaxf(xm, ALPHA * xm) * L2E;           // log2-domain row-max bound
    f32x4_t acc[NFB];
#pragma unroll
    for (int fb = 0; fb < NFB; fb++) acc[fb] = (f32x4_t)0.f;
    float rsum = 0.f;
    for (int st = 0; st < NW; st++) {
        int kb = k_begin + st * 32;
        float4 sa = *(const float4*)&s_k[kb + kg * 8];
        float4 sb = *(const float4*)&s_k[kb + kg * 8 + 4];
        unsigned int word = mask_lds[wave * 16 + fl][st];
        float sv[8] = { sa.x, sa.y, sa.z, sa.w, sb.x, sb.y, sb.z, sb.w };
        union { bf16x8_t v; unsigned short u[8]; } af;
#pragma unroll
        for (int j = 0; j < 8; j++) {
            float x = si + sv[j];
            float e = fmaxf(x, ALPHA * x);             // leakyrelu
            float p = EXP2F(fmaf(e, L2E, -rl2));       // unnormalized weight <= 1
            p = ((word >> (kg * 8 + j)) & 1u) ? p : 0.f;
            rsum += p;
            af.u[j] = f2bf_fast(p);
        }
        const unsigned short* bp = WhB + (size_t)(kb >> 5) * (NFB * 512) + (size_t)lane * 8;
#pragma unroll
        for (int fb = 0; fb < NFB; fb++) {
            bf16x8_t bfrag = *(const bf16x8_t*)(bp + (size_t)fb * 512);
            acc[fb] = __builtin_amdgcn_mfma_f32_16x16x32_bf16(af.v, bfrag, acc[fb], 0, 0, 0);
        }
    }
    // row-sum: lanes {l, l+16, l+32, l+48} hold partials of row R0+l
    rsum += __shfl_xor(rsum, 16);
    rsum += __shfl_xor(rsum, 32);
    if (lane < 16) partialS[(size_t)ks * M + R0 + lane] = rsum;
    // D layout: col = lane&15, row = (lane>>4)*4 + r
#pragma unroll
    for (int fb = 0; fb < NFB; fb++)
#pragma unroll
        for (int r = 0; r < 4; r++) {
            int ro = R0 + kg * 4 + r;
            partial[((size_t)ks * M + ro) * F + fb * 16 + fl] = acc[fb][r];
        }
}

// ---------------- fused: reduce partial1 -> normalize -> h1 (ELU) -> Wh2, WhB2, si2, sk2 ----
template <int KSPLIT>
__global__ __launch_bounds__(256) void fused_mid_kernel(const float* __restrict__ partial,
                                                        const float* __restrict__ partialS,
                                                        const float* __restrict__ W2,
                                                        const float* __restrict__ a2,
                                                        unsigned short* __restrict__ WhB2,
                                                        float* __restrict__ s_i2,
                                                        float* __restrict__ s_k2) {
    __shared__ float h_lds[4][64];
    int wave = threadIdx.x >> 6, lane = threadIdx.x & 63;
    int i = blockIdx.x * 4 + wave;
    float S = 0.f;
#pragma unroll
    for (int ks = 0; ks < KSPLIT; ks++) S += partialS[(size_t)ks * M + i];
    float rinv = S > 0.f ? 1.f / S : 0.f;
    float hv = 0.f;
#pragma unroll
    for (int ks = 0; ks < KSPLIT; ks++) hv += partial[((size_t)ks * M + i) * 64 + lane];
    hv *= rinv;
    hv = hv > 0.f ? hv : (__expf(hv) - 1.f);           // ELU -> h1[i][lane]
    h_lds[wave][lane] = hv;
    __syncthreads();
    int g = lane & 31, half = lane >> 5;
    float w2acc = 0.f;                                 // Wh2[i][g], split f-range by half
#pragma unroll
    for (int f = 0; f < 32; f++) {
        float hf = h_lds[wave][half * 32 + f];
        w2acc += hf * W2[(half * 32 + f) * 32 + g];
    }
    w2acc += __shfl_xor(w2acc, 32);
    float vi = w2acc * a2[g], vk = w2acc * a2[32 + g];
#pragma unroll
    for (int off = 16; off; off >>= 1) { vi += __shfl_xor(vi, off); vk += __shfl_xor(vk, off); }
    if (lane == 0) { s_i2[i] = vi; s_k2[i] = vk; }
    if (half == 0) {
        size_t idx = (((size_t)(i >> 5) * 2 + (g >> 4)) * 64 + (((i & 31) >> 3) * 16 + (g & 15))) * 8 + (i & 7);
        WhB2[idx] = f2bf(w2acc);
    }
}

// ---------------- fused: reduce partial2 -> normalize -> hL (ELU) -> out tail + omega dots ----
template <int KSPLIT>
__global__ __launch_bounds__(256) void fused_out_kernel(const float* __restrict__ partial,
                                                        const float* __restrict__ partialS,
                                                        const float* __restrict__ omega,
                                                        float* __restrict__ hL_out,
                                                        float* __restrict__ p_i,
                                                        float* __restrict__ p_k) {
    int wave = threadIdx.x >> 6, lane = threadIdx.x & 63;
    int i = blockIdx.x * 4 + wave;
    int g = lane & 31, half = lane >> 5;
    float S = 0.f;
#pragma unroll
    for (int ks = 0; ks < KSPLIT; ks++) S += partialS[(size_t)ks * M + i];
    float rinv = S > 0.f ? 1.f / S : 0.f;
    float hv = 0.f;
#pragma unroll
    for (int h = 0; h < KSPLIT / 2; h++) {
        int ks = half * (KSPLIT / 2) + h;
        hv += partial[((size_t)ks * M + i) * 32 + g];
    }
    hv += __shfl_xor(hv, 32);
    hv *= rinv;
    hv = hv > 0.f ? hv : (__expf(hv) - 1.f);
    if (half == 0) hL_out[(size_t)i * 32 + g] = hv;
    float vi = hv * omega[g], vk = hv * omega[32 + g];
#pragma unroll
    for (int off = 16; off; off >>= 1) { vi += __shfl_xor(vi, off); vk += __shfl_xor(vk, off); }
    if (lane == 0) { p_i[i] = vi; p_k[i] = vk; }
}

// ---------------- final pairwise sigmoid (grid-stride x4) ----------------
__global__ __launch_bounds__(256) void pred_kernel(const float* __restrict__ p_i,
                                                   const float* __restrict__ p_k,
                                                   float* __restrict__ out) {
    int gid = blockIdx.x * 256 + threadIdx.x;          // 0 .. M*M/16-1
#pragma unroll
    for (int t = 0; t < 4; t++) {
        int idx4 = gid + t * (M * M / 16);
        int i = idx4 / (M / 4);
        int k4 = (idx4 % (M / 4)) * 4;
        float pi = p_i[i];
        float4 pk = *(const float4*)&p_k[k4];
        float4 o;
        o.x = 1.f / (1.f + __expf(-(pi + pk.x)));
        o.y = 1.f / (1.f + __expf(-(pi + pk.y)));
        o.z = 1.f / (1.f + __expf(-(pi + pk.z)));
        o.w = 1.f / (1.f + __expf(-(pi + pk.w)));
        *(float4*)&out[(size_t)i * M + k4] = o;
    }
}

extern "C" void kernel_launch(void* const* d_in, const int* in_sizes, int n_in,
                              void* d_out, int out_size, void* d_ws, size_t ws_size,
                              hipStream_t stream) {
    const float* h0    = (const float*)d_in[0];
    const int*   adj   = (const int*)d_in[1];
    const float* W1    = (const float*)d_in[2];
    const float* a1    = (const float*)d_in[3];
    const float* W2    = (const float*)d_in[4];
    const float* a2    = (const float*)d_in[5];
    const float* omega = (const float*)d_in[6];
    float* out = (float*)d_out;

    char* ws = (char*)d_ws;
    unsigned int*   packedT = (unsigned int*)(ws + 0);         // 2 MB (transposed bits)
    unsigned short* WhB1    = (unsigned short*)(ws + 2097152); // 512 KB
    unsigned short* WhB2    = (unsigned short*)(ws + 2621440); // 256 KB
    float* si1 = (float*)(ws + 2883584);
    float* sk1 = (float*)(ws + 2899968);
    float* si2 = (float*)(ws + 2916352);
    float* sk2 = (float*)(ws + 2932736);
    float* pi  = (float*)(ws + 2949120);
    float* pk  = (float*)(ws + 2965504);
    float* pS1 = (float*)(ws + 2981888);   // KS*M*4 = 128 KB
    float* pS2 = (float*)(ws + 3112960);   // 128 KB

    float* partial = out;          // d_out as split-K scratch (pred overwrites later)
    constexpr int KS = 8;

    // pack (massively parallel streaming) + layer-1 GEMM/svec
    pack_kernel<<<M * M / 4 / 256, 256, 0, stream>>>(adj, packedT);
    fused_in_kernel<64, 64><<<M / 4, 256, 0, stream>>>(h0, W1, a1, WhB1, si1, sk1);
    attn_mfma_kernel<64, KS><<<(M / 64) * KS, 256, 0, stream>>>(WhB1, si1, sk1, packedT,
                                                                partial, pS1);

    // layer 2 (F=32), fused with layer-1 normalize+reduce
    fused_mid_kernel<KS><<<M / 4, 256, 0, stream>>>(partial, pS1, W2, a2, WhB2, si2, sk2);
    attn_mfma_kernel<32, KS><<<(M / 64) * KS, 256, 0, stream>>>(WhB2, si2, sk2, packedT,
                                                                partial, pS2);

    // link prediction
    fused_out_kernel<KS><<<M / 4, 256, 0, stream>>>(partial, pS2, omega, out + (size_t)M * M, pi, pk);
    pred_kernel<<<M * M / 16 / 256, 256, 0, stream>>>(pi, pk, out);
}